// Round 5
// baseline (269.481 us; speedup 1.0000x reference)
//
#include <hip/hip_runtime.h>

// All-pole time-varying IIR via chunked affine-state decomposition. 3 kernels:
// phase1: per-chunk affine maps (M_c,f_c), 31 lane-roles/chunk. VALU-bound bulk.
//         Mf layout [ch][row i<30][32 slots]: slot j<30 = M[i][j], slot 30 = f[i].
//         (row-major so phase2 reads rows as float4s; written coalesced across roles)
// phase2: per-batch serial scan s <- M_c s + f_c, 8x float4 row loads/lane,
//         readlane broadcast, depth-5 register prefetch.
// phase3: exact per-chunk re-run from known start state.
// Rules: all local-array indices compile-time static (rule #20, round-2 lesson);
// phase1 live-set must fit 128-VGPR granule (round-3 lesson);
// no LDS broadcast-scalar reads, no serialized staging (round-4 lesson).

#define Bb 64
#define Tt 16000
#define Nn 200
#define Pp 80
#define Mm 30

__device__ __forceinline__ float bcast(float v, int l) {
  return __uint_as_float(__builtin_amdgcn_readlane(__float_as_uint(v), l));
}

__device__ __forceinline__ void load_coeffs(const float* __restrict__ p0,
                                            const float* __restrict__ p1,
                                            float (&c0)[Mm], float (&dc)[Mm],
                                            float& K0, float& dK) {
  K0 = p0[0];
  dK = p1[0] - K0;
#pragma unroll
  for (int m = 0; m < Mm; ++m) {
    float v0 = p0[m + 1];
    c0[m] = v0;
    dc[m] = p1[m + 1] - v0;
  }
}

// ---------------- Phase 1 ----------------
template <int LCHUNK>
__global__ __launch_bounds__(256, 4) void phase1(const float* __restrict__ x,
                                                 const float* __restrict__ a,
                                                 float* __restrict__ Mf) {
  constexpr int C = Tt / LCHUNK;
  constexpr int NBLK = LCHUNK / 4;
  constexpr int FRAMES = LCHUNK / Pp;
  const int tid = threadIdx.x;
  const int wave = tid >> 6, lane = tid & 63, half = lane >> 5, role = lane & 31;
  const int ch = ((blockIdx.x * 4 + wave) << 1) + half;
  const int b = ch / C, c = ch % C;

  float hh[34];
#pragma unroll
  for (int i = 0; i < 34; ++i) hh[i] = (i < Mm && role == (29 - i)) ? 1.0f : 0.0f;
  const float gmask = (role == 30) ? 1.f : 0.f;

  const int n0 = c * FRAMES;
  const float* arow = a + ((size_t)b * Nn + n0) * 31;
  const float* arow1 = (n0 + 1 < Nn) ? arow + 31 : arow;
  float c0[Mm], dc[Mm], K0, dK;
  load_coeffs(arow, arow1, c0, dc, K0, dK);

  const float* xp = x + (size_t)b * Tt + c * LCHUNK;
  const float finc = 1.0f / Pp;
  float fbase = 0.f;

#pragma unroll 1
  for (int blk = 0; blk < NBLK; ++blk) {
    if constexpr (FRAMES == 2) {
      if (blk == NBLK / 2) {
        const int n = n0 + 1;
        const float* p0 = a + ((size_t)b * Nn + n) * 31;
        const float* p1 = (n + 1 < Nn) ? (p0 + 31) : p0;
        load_coeffs(p0, p1, c0, dc, K0, dK);
        fbase = 0.f;
      }
    }
    const float4 xq = *reinterpret_cast<const float4*>(xp + blk * 4);
#pragma unroll
    for (int k = 0; k < 4; ++k) {
      float a0 = 0.f, a1 = 0.f, d0 = 0.f, d1 = 0.f;
#pragma unroll
      for (int m = 0; m < Mm; m += 2) {
        float h0 = hh[29 + k - m];
        float h1 = hh[28 + k - m];
        a0 = fmaf(c0[m], h0, a0);
        d0 = fmaf(dc[m], h0, d0);
        a1 = fmaf(c0[m + 1], h1, a1);
        d1 = fmaf(dc[m + 1], h1, d1);
      }
      const float f = fmaf((float)k, finc, fbase);
      const float Kt = fmaf(dK, f, K0);
      const float xk = (k == 0) ? xq.x : (k == 1) ? xq.y : (k == 2) ? xq.z : xq.w;
      const float inp = gmask * (Kt * xk);
      const float y = fmaf(-f, d0 + d1, inp - (a0 + a1));
      hh[30 + k] = y;
    }
#pragma unroll
    for (int i = 0; i < 30; ++i) hh[i] = hh[i + 4];
    fbase += 4.0f * finc;
  }

  // store transposed: Mf[ch][i][role], coalesced across the 31 role-lanes
  if (role <= 30) {
    float* dst = Mf + (size_t)ch * 960 + role;
#pragma unroll
    for (int i = 0; i < 30; ++i) dst[i * 32] = hh[29 - i];
  }
}

// ---------------- Phase 2: per-batch serial scan ----------------
__device__ __forceinline__ void p2ld(const float* __restrict__ Mf, int ch, int lane,
                                     float (&R)[32]) {
  if (lane < Mm) {
    const float4* nb =
        reinterpret_cast<const float4*>(Mf + (size_t)ch * 960 + (size_t)lane * 32);
#pragma unroll
    for (int q = 0; q < 8; ++q) {
      float4 v = nb[q];
      R[4 * q + 0] = v.x;
      R[4 * q + 1] = v.y;
      R[4 * q + 2] = v.z;
      R[4 * q + 3] = v.w;
    }
  }
}

__device__ __forceinline__ float p2st(float s, const float (&R)[32]) {
  float a0 = R[30], a1 = 0.f;  // f[lane]
#pragma unroll
  for (int j = 0; j < Mm; j += 2) {
    a0 = fmaf(R[j], bcast(s, j), a0);
    a1 = fmaf(R[j + 1], bcast(s, j + 1), a1);
  }
  return a0 + a1;
}

template <int C>
__global__ __launch_bounds__(64, 1) void phase2(const float* __restrict__ Mf,
                                                float* __restrict__ Sstart) {
  const int b = blockIdx.x, lane = threadIdx.x;
  const int chbase = b * C;
  float s = 0.f;
  float R0[32], R1[32], R2[32], R3[32], R4[32];
  p2ld(Mf, chbase + 0, lane, R0);
  p2ld(Mf, chbase + 1, lane, R1);
  p2ld(Mf, chbase + 2, lane, R2);
  p2ld(Mf, chbase + 3, lane, R3);
  p2ld(Mf, chbase + 4, lane, R4);
#pragma unroll 1
  for (int c = 0; c < C; c += 5) {
    if (lane < Mm) Sstart[(size_t)(chbase + c) * 32 + lane] = s;
    s = p2st(s, R0);
    if (c + 5 < C) p2ld(Mf, chbase + c + 5, lane, R0);
    if (lane < Mm) Sstart[(size_t)(chbase + c + 1) * 32 + lane] = s;
    s = p2st(s, R1);
    if (c + 6 < C) p2ld(Mf, chbase + c + 6, lane, R1);
    if (lane < Mm) Sstart[(size_t)(chbase + c + 2) * 32 + lane] = s;
    s = p2st(s, R2);
    if (c + 7 < C) p2ld(Mf, chbase + c + 7, lane, R2);
    if (lane < Mm) Sstart[(size_t)(chbase + c + 3) * 32 + lane] = s;
    s = p2st(s, R3);
    if (c + 8 < C) p2ld(Mf, chbase + c + 8, lane, R3);
    if (lane < Mm) Sstart[(size_t)(chbase + c + 4) * 32 + lane] = s;
    s = p2st(s, R4);
    if (c + 9 < C) p2ld(Mf, chbase + c + 9, lane, R4);
  }
}

// ---------------- Phase 3: exact per-chunk re-run ----------------
template <int LCHUNK>
__global__ __launch_bounds__(64, 2) void phase3(const float* __restrict__ x,
                                                const float* __restrict__ a,
                                                const float* __restrict__ Sstart,
                                                float* __restrict__ out) {
  constexpr int C = Tt / LCHUNK;
  constexpr int NBLK = LCHUNK / 4;
  constexpr int FRAMES = LCHUNK / Pp;
  const int ch = blockIdx.x * 64 + threadIdx.x;
  const int b = ch / C, c = ch % C;

  float sv[32];
  {
    const float4* sp4 = reinterpret_cast<const float4*>(Sstart + (size_t)ch * 32);
#pragma unroll
    for (int q = 0; q < 8; ++q) {
      float4 v = sp4[q];
      sv[4 * q + 0] = v.x;
      sv[4 * q + 1] = v.y;
      sv[4 * q + 2] = v.z;
      sv[4 * q + 3] = v.w;
    }
  }
  float hh[34];
#pragma unroll
  for (int m = 0; m < Mm; ++m) hh[29 - m] = sv[m];
#pragma unroll
  for (int i = 30; i < 34; ++i) hh[i] = 0.f;

  const int n0 = c * FRAMES;
  const float* arow = a + ((size_t)b * Nn + n0) * 31;
  const float* arow1 = (n0 + 1 < Nn) ? arow + 31 : arow;
  float c0[Mm], dc[Mm], K0, dK;
  load_coeffs(arow, arow1, c0, dc, K0, dK);

  const float* xp = x + (size_t)b * Tt + c * LCHUNK;
  float* yp = out + (size_t)b * Tt + c * LCHUNK;
  const float finc = 1.0f / Pp;
  float fbase = 0.f;

#pragma unroll 1
  for (int blk = 0; blk < NBLK; ++blk) {
    if constexpr (FRAMES == 2) {
      if (blk == NBLK / 2) {
        const int n = n0 + 1;
        const float* p0 = a + ((size_t)b * Nn + n) * 31;
        const float* p1 = (n + 1 < Nn) ? (p0 + 31) : p0;
        load_coeffs(p0, p1, c0, dc, K0, dK);
        fbase = 0.f;
      }
    }
    const float4 xq = *reinterpret_cast<const float4*>(xp + blk * 4);
    float y0, y1, y2, y3;
#pragma unroll
    for (int k = 0; k < 4; ++k) {
      float a0 = 0.f, a1 = 0.f, d0 = 0.f, d1 = 0.f;
#pragma unroll
      for (int m = 0; m < Mm; m += 2) {
        float h0 = hh[29 + k - m];
        float h1 = hh[28 + k - m];
        a0 = fmaf(c0[m], h0, a0);
        d0 = fmaf(dc[m], h0, d0);
        a1 = fmaf(c0[m + 1], h1, a1);
        d1 = fmaf(dc[m + 1], h1, d1);
      }
      const float f = fmaf((float)k, finc, fbase);
      const float Kt = fmaf(dK, f, K0);
      const float xk = (k == 0) ? xq.x : (k == 1) ? xq.y : (k == 2) ? xq.z : xq.w;
      const float y = fmaf(-f, d0 + d1, fmaf(Kt, xk, -(a0 + a1)));
      hh[30 + k] = y;
      if (k == 0) y0 = y;
      else if (k == 1) y1 = y;
      else if (k == 2) y2 = y;
      else y3 = y;
    }
    *reinterpret_cast<float4*>(yp + blk * 4) = make_float4(y0, y1, y2, y3);
#pragma unroll
    for (int i = 0; i < 30; ++i) hh[i] = hh[i + 4];
    fbase += 4.0f * finc;
  }
}

// ---------------- Naive fallback ----------------
__global__ void naive_kernel(const float* __restrict__ x, const float* __restrict__ a,
                             float* __restrict__ out) {
  const int b = blockIdx.x * blockDim.x + threadIdx.x;
  if (b >= Bb) return;
  float h[Mm];
#pragma unroll
  for (int m = 0; m < Mm; ++m) h[m] = 0.f;
  for (int n = 0; n < Nn; ++n) {
    const float* p0 = a + ((size_t)b * Nn + n) * 31;
    const float* p1 = a + ((size_t)b * Nn + min(n + 1, Nn - 1)) * 31;
    float c0[Mm], dc[Mm];
#pragma unroll
    for (int m = 0; m < Mm; ++m) {
      float v0 = p0[m + 1];
      c0[m] = v0;
      dc[m] = p1[m + 1] - v0;
    }
    const float K0 = p0[0], dK = p1[0] - K0;
    const float* xp = x + (size_t)b * Tt + n * Pp;
    float* yp = out + (size_t)b * Tt + n * Pp;
    for (int i = 0; i < Pp; ++i) {
      const float f = (float)i * (1.0f / Pp);
      float acc = 0.f;
#pragma unroll
      for (int m = 0; m < Mm; ++m) acc = fmaf(fmaf(dc[m], f, c0[m]), h[m], acc);
      const float y = fmaf(fmaf(dK, f, K0), xp[i], -acc);
      yp[i] = y;
#pragma unroll
      for (int m = Mm - 1; m > 0; --m) h[m] = h[m - 1];
      h[0] = y;
    }
  }
}

template <int LCHUNK>
static void run_pipeline(const float* x, const float* a, float* out, float* ws,
                         hipStream_t stream) {
  constexpr int C = Tt / LCHUNK;
  float* Mf = ws;                            // Bb*C*960 floats
  float* Sstart = ws + (size_t)Bb * C * 960; // Bb*C*32 floats
  phase1<LCHUNK><<<Bb * C / 8, 256, 0, stream>>>(x, a, Mf);
  phase2<C><<<Bb, 64, 0, stream>>>(Mf, Sstart);
  phase3<LCHUNK><<<Bb * C / 64, 64, 0, stream>>>(x, a, Sstart, out);
}

extern "C" void kernel_launch(void* const* d_in, const int* in_sizes, int n_in,
                              void* d_out, int out_size, void* d_ws, size_t ws_size,
                              hipStream_t stream) {
  const float* x = (const float*)d_in[0];  // (64,16000) f32
  const float* a = (const float*)d_in[1];  // (64,200,31) f32
  float* out = (float*)d_out;              // (64,16000) f32

  auto need = [](int C) -> size_t { return ((size_t)Bb * C * 960 + (size_t)Bb * C * 32) * 4; };

  if (ws_size >= need(200)) {
    run_pipeline<80>(x, a, out, (float*)d_ws, stream);
  } else if (ws_size >= need(100)) {
    run_pipeline<160>(x, a, out, (float*)d_ws, stream);
  } else {
    naive_kernel<<<1, 64, 0, stream>>>(x, a, out);
  }
}

// Round 6
// 249.466 us; speedup vs baseline: 1.0802x; 1.0802x over previous
//
#include <hip/hip_runtime.h>

// All-pole time-varying IIR via chunked affine-state decomposition.
// y[t] = K[t]*x[t] - sum_m A[t][m]*y[t-1-m], coeffs lin-interp per 80-sample frame.
// C=100 chunks of L=160. phase1 builds per-chunk affine maps (M_c,f_c); phase2 scans
// them per batch; phase3 re-runs chunks exactly from known start states.
//
// KEY STRUCTURE (round-6): pair-lane tap-split IIR core. Each role (= matrix column
// or output run) is handled by a LANE PAIR: even lane owns taps m=0..14 (recent
// history), odd lane owns m=15..29 (old history, window stored REVERSED so both
// lanes run the IDENTICAL instruction stream on different data — no exec divergence).
// Per step one __shfl_xor(partial,1); per 4-step block 4 shfls hand aged y values
// across the age-15 boundary. Live set ~70 floats -> no scratch spill (rounds 3-5
// post-mortem: the ~105-float live set of the fused core spilled; phase3 at 100-200
// waves was latency-exposed scratch => ~85us hidden sink).
// Rules: static local-array indices only (rule #20); phase2 readlane broadcast.

#define Bb 64
#define Tt 16000
#define Nn 200
#define Pp 80
#define Mm 30
#define Cc 100
#define Ll 160
#define NBLK (Ll / 4)  // 40

#define MF_FLOATS ((size_t)Bb * Cc * 930)
#define SS_FLOATS ((size_t)Bb * Cc * 32)

__device__ __forceinline__ float bcast(float v, int l) {
  return __uint_as_float(__builtin_amdgcn_readlane(__float_as_uint(v), l));
}

// load this lane's 15-tap coefficient half (boff = 15 for even/recent, 30 for odd/old)
__device__ __forceinline__ void load_half(const float* __restrict__ p0,
                                          const float* __restrict__ p1, int boff,
                                          float (&cf)[15], float (&df)[15],
                                          float& K0, float& dK) {
  K0 = p0[0];
  dK = p1[0] - K0;
#pragma unroll
  for (int j = 0; j < 15; ++j) {
    float v0 = p0[boff - j];
    cf[j] = v0;
    df[j] = p1[boff - j] - v0;
  }
}

// ---------------- Phase 1: per-chunk transition matrices ----------------
// wave = one chunk; lanes 2r,2r+1 = role r (r=0..30: 30 unit-state cols + input run).
__global__ __launch_bounds__(256, 6) void phase1(const float* __restrict__ x,
                                                 const float* __restrict__ a,
                                                 float* __restrict__ Mf) {
  const int tid = threadIdx.x;
  const int wch = blockIdx.x * 4 + (tid >> 6);  // chunk id = b*Cc + c
  const int lane = tid & 63;
  const int role = lane >> 1;
  const int isB = lane & 1;  // 0 = recent taps, 1 = old taps
  const int b = wch / Cc, c = wch % Cc;
  const float gmask = (lane == 60) ? 1.f : 0.f;  // role 30, even lane: input-driven

  // window: even w[i]=y[t-15+i]; odd w[i]=y[t-30+i] (i=0..14 valid at block start)
  float w[19];
  const int sbase = isB ? 29 : 14;  // initial state e_role: w[i]=s[sbase-i]
#pragma unroll
  for (int i = 0; i < 19; ++i) w[i] = (i < 15 && (sbase - i) == role) ? 1.f : 0.f;

  const int n0 = 2 * c;
  const float* ar = a + ((size_t)b * Nn + n0) * 31;
  const int boff = isB ? 30 : 15;
  float cf[15], df[15], K0, dK;
  load_half(ar, ar + 31, boff, cf, df, K0, dK);

  const float* xp = x + (size_t)b * Tt + c * Ll;
  const float finc = 1.0f / Pp;
  float fbase = 0.f;

#pragma unroll 1
  for (int blk = 0; blk < NBLK; ++blk) {
    if (blk == NBLK / 2) {
      const float* p0 = ar + 31;
      const float* p1 = (n0 + 2 < Nn) ? p0 + 31 : p0;
      load_half(p0, p1, boff, cf, df, K0, dK);
      fbase = 0.f;
    }
    const float4 xq = *reinterpret_cast<const float4*>(xp + blk * 4);
    float recv[4];
#pragma unroll
    for (int k = 0; k < 4; ++k) recv[k] = __shfl_xor(w[k], 1, 64);
#pragma unroll
    for (int k = 0; k < 4; ++k) {
      float aa = 0.f, ab = 0.f, dd = 0.f, db = 0.f;
#pragma unroll
      for (int j = 0; j < 14; j += 2) {
        aa = fmaf(cf[j], w[j + k], aa);
        dd = fmaf(df[j], w[j + k], dd);
        ab = fmaf(cf[j + 1], w[j + 1 + k], ab);
        db = fmaf(df[j + 1], w[j + 1 + k], db);
      }
      aa = fmaf(cf[14], w[14 + k], aa);
      dd = fmaf(df[14], w[14 + k], dd);
      const float f = fmaf((float)k, finc, fbase);
      const float p = fmaf(f, dd + db, aa + ab);
      const float q = __shfl_xor(p, 1, 64);
      const float Kt = fmaf(dK, f, K0);
      const float xk = (k == 0) ? xq.x : (k == 1) ? xq.y : (k == 2) ? xq.z : xq.w;
      const float y = fmaf(gmask, Kt * xk, -(p + q));
      w[15 + k] = isB ? recv[k] : y;
    }
#pragma unroll
    for (int i = 0; i < 15; ++i) w[i] = w[i + 4];
    fbase += 4.0f * finc;
  }

  // store column `role`: rows 0-14 from even lane, 15-29 from odd; s_end[j]=w[14-j]
  if (role <= 30) {
    float* dst = Mf + (size_t)wch * 930 + role * 30 + (isB ? 15 : 0);
#pragma unroll
    for (int j = 0; j < 15; ++j) dst[j] = w[14 - j];
  }
}

// ---------------- Phase 2: per-batch serial scan (readlane, depth-4) ----------------
__device__ __forceinline__ void p2ld(const float* __restrict__ Mf, int ch, int lane,
                                     float (&R)[31]) {
  const float* nb = Mf + (size_t)ch * 930;
  if (lane < Mm) {
#pragma unroll
    for (int j = 0; j < 31; ++j) R[j] = nb[j * 30 + lane];  // R[j]=M[lane][j], R[30]=f
  }
}

__device__ __forceinline__ float p2st(float s, const float (&R)[31]) {
  float a0 = R[30], a1 = 0.f;
#pragma unroll
  for (int j = 0; j < Mm; j += 2) {
    a0 = fmaf(R[j], bcast(s, j), a0);
    a1 = fmaf(R[j + 1], bcast(s, j + 1), a1);
  }
  return a0 + a1;
}

__global__ __launch_bounds__(64, 1) void phase2(const float* __restrict__ Mf,
                                                float* __restrict__ Sstart) {
  const int b = blockIdx.x, lane = threadIdx.x;
  const int chb = b * Cc;
  float s = 0.f;
  float R0[31], R1[31], R2[31], R3[31];
  p2ld(Mf, chb + 0, lane, R0);
  p2ld(Mf, chb + 1, lane, R1);
  p2ld(Mf, chb + 2, lane, R2);
  p2ld(Mf, chb + 3, lane, R3);
#pragma unroll 1
  for (int c = 0; c < Cc; c += 4) {
    if (lane < Mm) Sstart[(size_t)(chb + c) * 32 + lane] = s;
    s = p2st(s, R0);
    if (c + 4 < Cc) p2ld(Mf, chb + c + 4, lane, R0);
    if (lane < Mm) Sstart[(size_t)(chb + c + 1) * 32 + lane] = s;
    s = p2st(s, R1);
    if (c + 5 < Cc) p2ld(Mf, chb + c + 5, lane, R1);
    if (lane < Mm) Sstart[(size_t)(chb + c + 2) * 32 + lane] = s;
    s = p2st(s, R2);
    if (c + 6 < Cc) p2ld(Mf, chb + c + 6, lane, R2);
    if (lane < Mm) Sstart[(size_t)(chb + c + 3) * 32 + lane] = s;
    s = p2st(s, R3);
    if (c + 7 < Cc) p2ld(Mf, chb + c + 7, lane, R3);
  }
}

// ---------------- Phase 3: exact re-run, lane-pair per chunk ----------------
__global__ __launch_bounds__(256, 4) void phase3(const float* __restrict__ x,
                                                 const float* __restrict__ a,
                                                 const float* __restrict__ Sstart,
                                                 float* __restrict__ out) {
  const int gtid = blockIdx.x * 256 + threadIdx.x;  // 50 blocks * 256 = 12800
  const int ch = gtid >> 1;
  const int isB = gtid & 1;
  const int b = ch / Cc, c = ch % Cc;
  const float gmask = isB ? 0.f : 1.f;

  const float* sp = Sstart + (size_t)ch * 32;
  const int sbase = isB ? 29 : 14;
  float w[19];
#pragma unroll
  for (int i = 0; i < 15; ++i) w[i] = sp[sbase - i];
#pragma unroll
  for (int i = 15; i < 19; ++i) w[i] = 0.f;

  const int n0 = 2 * c;
  const float* ar = a + ((size_t)b * Nn + n0) * 31;
  const int boff = isB ? 30 : 15;
  float cf[15], df[15], K0, dK;
  load_half(ar, ar + 31, boff, cf, df, K0, dK);

  const float* xp = x + (size_t)b * Tt + c * Ll;
  float* yp = out + (size_t)b * Tt + c * Ll;
  const float finc = 1.0f / Pp;
  float fbase = 0.f;

#pragma unroll 1
  for (int blk = 0; blk < NBLK; ++blk) {
    if (blk == NBLK / 2) {
      const float* p0 = ar + 31;
      const float* p1 = (n0 + 2 < Nn) ? p0 + 31 : p0;
      load_half(p0, p1, boff, cf, df, K0, dK);
      fbase = 0.f;
    }
    const float4 xq = *reinterpret_cast<const float4*>(xp + blk * 4);
    float recv[4];
#pragma unroll
    for (int k = 0; k < 4; ++k) recv[k] = __shfl_xor(w[k], 1, 64);
#pragma unroll
    for (int k = 0; k < 4; ++k) {
      float aa = 0.f, ab = 0.f, dd = 0.f, db = 0.f;
#pragma unroll
      for (int j = 0; j < 14; j += 2) {
        aa = fmaf(cf[j], w[j + k], aa);
        dd = fmaf(df[j], w[j + k], dd);
        ab = fmaf(cf[j + 1], w[j + 1 + k], ab);
        db = fmaf(df[j + 1], w[j + 1 + k], db);
      }
      aa = fmaf(cf[14], w[14 + k], aa);
      dd = fmaf(df[14], w[14 + k], dd);
      const float f = fmaf((float)k, finc, fbase);
      const float p = fmaf(f, dd + db, aa + ab);
      const float q = __shfl_xor(p, 1, 64);
      const float Kt = fmaf(dK, f, K0);
      const float xk = (k == 0) ? xq.x : (k == 1) ? xq.y : (k == 2) ? xq.z : xq.w;
      const float y = fmaf(gmask, Kt * xk, -(p + q));
      w[15 + k] = isB ? recv[k] : y;
    }
    if (!isB) {
      *reinterpret_cast<float4*>(yp + blk * 4) = make_float4(w[15], w[16], w[17], w[18]);
    }
#pragma unroll
    for (int i = 0; i < 15; ++i) w[i] = w[i + 4];
    fbase += 4.0f * finc;
  }
}

// ---------------- Naive fallback ----------------
__global__ void naive_kernel(const float* __restrict__ x, const float* __restrict__ a,
                             float* __restrict__ out) {
  const int b = blockIdx.x * blockDim.x + threadIdx.x;
  if (b >= Bb) return;
  float h[Mm];
#pragma unroll
  for (int m = 0; m < Mm; ++m) h[m] = 0.f;
  for (int n = 0; n < Nn; ++n) {
    const float* p0 = a + ((size_t)b * Nn + n) * 31;
    const float* p1 = a + ((size_t)b * Nn + min(n + 1, Nn - 1)) * 31;
    float c0[Mm], dc[Mm];
#pragma unroll
    for (int m = 0; m < Mm; ++m) {
      float v0 = p0[m + 1];
      c0[m] = v0;
      dc[m] = p1[m + 1] - v0;
    }
    const float K0 = p0[0], dK = p1[0] - K0;
    const float* xp = x + (size_t)b * Tt + n * Pp;
    float* yp = out + (size_t)b * Tt + n * Pp;
    for (int i = 0; i < Pp; ++i) {
      const float f = (float)i * (1.0f / Pp);
      float acc = 0.f;
#pragma unroll
      for (int m = 0; m < Mm; ++m) acc = fmaf(fmaf(dc[m], f, c0[m]), h[m], acc);
      const float y = fmaf(fmaf(dK, f, K0), xp[i], -acc);
      yp[i] = y;
#pragma unroll
      for (int m = Mm - 1; m > 0; --m) h[m] = h[m - 1];
      h[0] = y;
    }
  }
}

extern "C" void kernel_launch(void* const* d_in, const int* in_sizes, int n_in,
                              void* d_out, int out_size, void* d_ws, size_t ws_size,
                              hipStream_t stream) {
  const float* x = (const float*)d_in[0];  // (64,16000) f32
  const float* a = (const float*)d_in[1];  // (64,200,31) f32
  float* out = (float*)d_out;              // (64,16000) f32

  const size_t need = (MF_FLOATS + SS_FLOATS) * sizeof(float);
  if (ws_size < need) {
    naive_kernel<<<1, 64, 0, stream>>>(x, a, out);
    return;
  }
  float* Mf = (float*)d_ws;
  float* Sstart = Mf + MF_FLOATS;

  // 6400 chunk-waves, 4 per block
  phase1<<<Bb * Cc / 4, 256, 0, stream>>>(x, a, Mf);
  phase2<<<Bb, 64, 0, stream>>>(Mf, Sstart);
  // 6400 chunks x 2 lanes = 12800 threads
  phase3<<<Bb * Cc * 2 / 256, 256, 0, stream>>>(x, a, Sstart, out);
}

// Round 7
// 206.472 us; speedup vs baseline: 1.3052x; 1.2082x over previous
//
#include <hip/hip_runtime.h>

// All-pole time-varying IIR via chunked affine-state decomposition.
// y[t] = K[t]*x[t] - sum_m A[t][m]*y[t-1-m], coeffs lin-interp per 80-sample frame.
// C=100 chunks of L=160. phase1 builds per-chunk affine maps (M_c,f_c); phase2 scans
// them per batch; phase3 re-runs chunks exactly from known start states.
//
// Pair-lane tap-split IIR core: each role (matrix column / output run) is a LANE
// PAIR: even lane owns taps m=0..14 (recent), odd lane owns m=15..29 (old, window
// REVERSED so both lanes run identical instructions). One __shfl_xor(partial,1)
// per step; 4 shfls per 4-step block hand aged y across the age-15 boundary.
// Live set ~70 floats.
//
// Lessons encoded: static local-array indices only (r2); launch_bounds min-waves
// must leave VGPR headroom - (256,6) forced spill-collapse to VGPR=40 + 76MB
// scratch (r6); column-contiguous Mf stores only - transposed stride-32 store
// caused 6x write amplification (r5).

#define Bb 64
#define Tt 16000
#define Nn 200
#define Pp 80
#define Mm 30
#define Cc 100
#define Ll 160
#define NBLK (Ll / 4)  // 40

#define MF_FLOATS ((size_t)Bb * Cc * 930)
#define SS_FLOATS ((size_t)Bb * Cc * 32)

__device__ __forceinline__ float bcast(float v, int l) {
  return __uint_as_float(__builtin_amdgcn_readlane(__float_as_uint(v), l));
}

// load this lane's 15-tap coefficient half (boff = 15 for even/recent, 30 for odd/old)
__device__ __forceinline__ void load_half(const float* __restrict__ p0,
                                          const float* __restrict__ p1, int boff,
                                          float (&cf)[15], float (&df)[15],
                                          float& K0, float& dK) {
  K0 = p0[0];
  dK = p1[0] - K0;
#pragma unroll
  for (int j = 0; j < 15; ++j) {
    float v0 = p0[boff - j];
    cf[j] = v0;
    df[j] = p1[boff - j] - v0;
  }
}

// ---------------- Phase 1: per-chunk transition matrices ----------------
// wave = one chunk; lanes 2r,2r+1 = role r (r=0..30: 30 unit-state cols + input run).
__global__ __launch_bounds__(256, 4) void phase1(const float* __restrict__ x,
                                                 const float* __restrict__ a,
                                                 float* __restrict__ Mf) {
  const int tid = threadIdx.x;
  const int wch = blockIdx.x * 4 + (tid >> 6);  // chunk id = b*Cc + c
  const int lane = tid & 63;
  const int role = lane >> 1;
  const int isB = lane & 1;  // 0 = recent taps, 1 = old taps
  const int b = wch / Cc, c = wch % Cc;
  const float gmask = (lane == 60) ? 1.f : 0.f;  // role 30, even lane: input-driven

  // window: even w[i]=y[t-15+i]; odd w[i]=y[t-30+i] (i=0..14 valid at block start)
  float w[19];
  const int sbase = isB ? 29 : 14;  // initial state e_role: w[i]=s[sbase-i]
#pragma unroll
  for (int i = 0; i < 19; ++i) w[i] = (i < 15 && (sbase - i) == role) ? 1.f : 0.f;

  const int n0 = 2 * c;
  const float* ar = a + ((size_t)b * Nn + n0) * 31;
  const int boff = isB ? 30 : 15;
  float cf[15], df[15], K0, dK;
  load_half(ar, ar + 31, boff, cf, df, K0, dK);

  const float* xp = x + (size_t)b * Tt + c * Ll;
  const float finc = 1.0f / Pp;
  float fbase = 0.f;

#pragma unroll 1
  for (int blk = 0; blk < NBLK; ++blk) {
    if (blk == NBLK / 2) {
      const float* p0 = ar + 31;
      const float* p1 = (n0 + 2 < Nn) ? p0 + 31 : p0;
      load_half(p0, p1, boff, cf, df, K0, dK);
      fbase = 0.f;
    }
    const float4 xq = *reinterpret_cast<const float4*>(xp + blk * 4);
    float recv[4];
#pragma unroll
    for (int k = 0; k < 4; ++k) recv[k] = __shfl_xor(w[k], 1, 64);
#pragma unroll
    for (int k = 0; k < 4; ++k) {
      float aa = 0.f, ab = 0.f, dd = 0.f, db = 0.f;
#pragma unroll
      for (int j = 0; j < 14; j += 2) {
        aa = fmaf(cf[j], w[j + k], aa);
        dd = fmaf(df[j], w[j + k], dd);
        ab = fmaf(cf[j + 1], w[j + 1 + k], ab);
        db = fmaf(df[j + 1], w[j + 1 + k], db);
      }
      aa = fmaf(cf[14], w[14 + k], aa);
      dd = fmaf(df[14], w[14 + k], dd);
      const float f = fmaf((float)k, finc, fbase);
      const float p = fmaf(f, dd + db, aa + ab);
      const float q = __shfl_xor(p, 1, 64);
      const float Kt = fmaf(dK, f, K0);
      const float xk = (k == 0) ? xq.x : (k == 1) ? xq.y : (k == 2) ? xq.z : xq.w;
      const float y = fmaf(gmask, Kt * xk, -(p + q));
      w[15 + k] = isB ? recv[k] : y;
    }
#pragma unroll
    for (int i = 0; i < 15; ++i) w[i] = w[i + 4];
    fbase += 4.0f * finc;
  }

  // store column `role`: rows 0-14 from even lane, 15-29 from odd; s_end[j]=w[14-j]
  if (role <= 30) {
    float* dst = Mf + (size_t)wch * 930 + role * 30 + (isB ? 15 : 0);
#pragma unroll
    for (int j = 0; j < 15; ++j) dst[j] = w[14 - j];
  }
}

// ---------------- Phase 2: per-batch serial scan (readlane, depth-4) ----------------
__device__ __forceinline__ void p2ld(const float* __restrict__ Mf, int ch, int lane,
                                     float (&R)[31]) {
  const float* nb = Mf + (size_t)ch * 930;
  if (lane < Mm) {
#pragma unroll
    for (int j = 0; j < 31; ++j) R[j] = nb[j * 30 + lane];  // R[j]=M[lane][j], R[30]=f
  }
}

__device__ __forceinline__ float p2st(float s, const float (&R)[31]) {
  float a0 = R[30], a1 = 0.f;
#pragma unroll
  for (int j = 0; j < Mm; j += 2) {
    a0 = fmaf(R[j], bcast(s, j), a0);
    a1 = fmaf(R[j + 1], bcast(s, j + 1), a1);
  }
  return a0 + a1;
}

__global__ __launch_bounds__(64, 1) void phase2(const float* __restrict__ Mf,
                                                float* __restrict__ Sstart) {
  const int b = blockIdx.x, lane = threadIdx.x;
  const int chb = b * Cc;
  float s = 0.f;
  float R0[31], R1[31], R2[31], R3[31];
  p2ld(Mf, chb + 0, lane, R0);
  p2ld(Mf, chb + 1, lane, R1);
  p2ld(Mf, chb + 2, lane, R2);
  p2ld(Mf, chb + 3, lane, R3);
#pragma unroll 1
  for (int c = 0; c < Cc; c += 4) {
    if (lane < Mm) Sstart[(size_t)(chb + c) * 32 + lane] = s;
    s = p2st(s, R0);
    if (c + 4 < Cc) p2ld(Mf, chb + c + 4, lane, R0);
    if (lane < Mm) Sstart[(size_t)(chb + c + 1) * 32 + lane] = s;
    s = p2st(s, R1);
    if (c + 5 < Cc) p2ld(Mf, chb + c + 5, lane, R1);
    if (lane < Mm) Sstart[(size_t)(chb + c + 2) * 32 + lane] = s;
    s = p2st(s, R2);
    if (c + 6 < Cc) p2ld(Mf, chb + c + 6, lane, R2);
    if (lane < Mm) Sstart[(size_t)(chb + c + 3) * 32 + lane] = s;
    s = p2st(s, R3);
    if (c + 7 < Cc) p2ld(Mf, chb + c + 7, lane, R3);
  }
}

// ---------------- Phase 3: exact re-run, lane-pair per chunk ----------------
__global__ __launch_bounds__(256, 4) void phase3(const float* __restrict__ x,
                                                 const float* __restrict__ a,
                                                 const float* __restrict__ Sstart,
                                                 float* __restrict__ out) {
  const int gtid = blockIdx.x * 256 + threadIdx.x;  // 50 blocks * 256 = 12800
  const int ch = gtid >> 1;
  const int isB = gtid & 1;
  const int b = ch / Cc, c = ch % Cc;
  const float gmask = isB ? 0.f : 1.f;

  const float* sp = Sstart + (size_t)ch * 32;
  const int sbase = isB ? 29 : 14;
  float w[19];
#pragma unroll
  for (int i = 0; i < 15; ++i) w[i] = sp[sbase - i];
#pragma unroll
  for (int i = 15; i < 19; ++i) w[i] = 0.f;

  const int n0 = 2 * c;
  const float* ar = a + ((size_t)b * Nn + n0) * 31;
  const int boff = isB ? 30 : 15;
  float cf[15], df[15], K0, dK;
  load_half(ar, ar + 31, boff, cf, df, K0, dK);

  const float* xp = x + (size_t)b * Tt + c * Ll;
  float* yp = out + (size_t)b * Tt + c * Ll;
  const float finc = 1.0f / Pp;
  float fbase = 0.f;

#pragma unroll 1
  for (int blk = 0; blk < NBLK; ++blk) {
    if (blk == NBLK / 2) {
      const float* p0 = ar + 31;
      const float* p1 = (n0 + 2 < Nn) ? p0 + 31 : p0;
      load_half(p0, p1, boff, cf, df, K0, dK);
      fbase = 0.f;
    }
    const float4 xq = *reinterpret_cast<const float4*>(xp + blk * 4);
    float recv[4];
#pragma unroll
    for (int k = 0; k < 4; ++k) recv[k] = __shfl_xor(w[k], 1, 64);
#pragma unroll
    for (int k = 0; k < 4; ++k) {
      float aa = 0.f, ab = 0.f, dd = 0.f, db = 0.f;
#pragma unroll
      for (int j = 0; j < 14; j += 2) {
        aa = fmaf(cf[j], w[j + k], aa);
        dd = fmaf(df[j], w[j + k], dd);
        ab = fmaf(cf[j + 1], w[j + 1 + k], ab);
        db = fmaf(df[j + 1], w[j + 1 + k], db);
      }
      aa = fmaf(cf[14], w[14 + k], aa);
      dd = fmaf(df[14], w[14 + k], dd);
      const float f = fmaf((float)k, finc, fbase);
      const float p = fmaf(f, dd + db, aa + ab);
      const float q = __shfl_xor(p, 1, 64);
      const float Kt = fmaf(dK, f, K0);
      const float xk = (k == 0) ? xq.x : (k == 1) ? xq.y : (k == 2) ? xq.z : xq.w;
      const float y = fmaf(gmask, Kt * xk, -(p + q));
      w[15 + k] = isB ? recv[k] : y;
    }
    if (!isB) {
      *reinterpret_cast<float4*>(yp + blk * 4) = make_float4(w[15], w[16], w[17], w[18]);
    }
#pragma unroll
    for (int i = 0; i < 15; ++i) w[i] = w[i + 4];
    fbase += 4.0f * finc;
  }
}

// ---------------- Naive fallback ----------------
__global__ void naive_kernel(const float* __restrict__ x, const float* __restrict__ a,
                             float* __restrict__ out) {
  const int b = blockIdx.x * blockDim.x + threadIdx.x;
  if (b >= Bb) return;
  float h[Mm];
#pragma unroll
  for (int m = 0; m < Mm; ++m) h[m] = 0.f;
  for (int n = 0; n < Nn; ++n) {
    const float* p0 = a + ((size_t)b * Nn + n) * 31;
    const float* p1 = a + ((size_t)b * Nn + min(n + 1, Nn - 1)) * 31;
    float c0[Mm], dc[Mm];
#pragma unroll
    for (int m = 0; m < Mm; ++m) {
      float v0 = p0[m + 1];
      c0[m] = v0;
      dc[m] = p1[m + 1] - v0;
    }
    const float K0 = p0[0], dK = p1[0] - K0;
    const float* xp = x + (size_t)b * Tt + n * Pp;
    float* yp = out + (size_t)b * Tt + n * Pp;
    for (int i = 0; i < Pp; ++i) {
      const float f = (float)i * (1.0f / Pp);
      float acc = 0.f;
#pragma unroll
      for (int m = 0; m < Mm; ++m) acc = fmaf(fmaf(dc[m], f, c0[m]), h[m], acc);
      const float y = fmaf(fmaf(dK, f, K0), xp[i], -acc);
      yp[i] = y;
#pragma unroll
      for (int m = Mm - 1; m > 0; --m) h[m] = h[m - 1];
      h[0] = y;
    }
  }
}

extern "C" void kernel_launch(void* const* d_in, const int* in_sizes, int n_in,
                              void* d_out, int out_size, void* d_ws, size_t ws_size,
                              hipStream_t stream) {
  const float* x = (const float*)d_in[0];  // (64,16000) f32
  const float* a = (const float*)d_in[1];  // (64,200,31) f32
  float* out = (float*)d_out;              // (64,16000) f32

  const size_t need = (MF_FLOATS + SS_FLOATS) * sizeof(float);
  if (ws_size < need) {
    naive_kernel<<<1, 64, 0, stream>>>(x, a, out);
    return;
  }
  float* Mf = (float*)d_ws;
  float* Sstart = Mf + MF_FLOATS;

  // 6400 chunk-waves, 4 per block
  phase1<<<Bb * Cc / 4, 256, 0, stream>>>(x, a, Mf);
  phase2<<<Bb, 64, 0, stream>>>(Mf, Sstart);
  // 6400 chunks x 2 lanes = 12800 threads
  phase3<<<Bb * Cc * 2 / 256, 256, 0, stream>>>(x, a, Sstart, out);
}